// Round 9
// baseline (271.712 us; speedup 1.0000x reference)
//
#include <hip/hip_runtime.h>
#include <hip/hip_bf16.h>
#include <math.h>

#define S_NODES 255
#define B_TREES 256
#define F_IN 64
#define H_DIM 128

typedef __attribute__((ext_vector_type(8))) short short8;
typedef __attribute__((ext_vector_type(4))) float f32x4;

__device__ __forceinline__ float fsig(float x) {
    float e = __expf(-x);
    return __builtin_amdgcn_rcpf(1.0f + e);
}
__device__ __forceinline__ float ftanh_(float x) {
    x = fminf(fmaxf(x, -15.0f), 15.0f);
    float e = __expf(2.0f * x);
    return (e - 1.0f) * __builtin_amdgcn_rcpf(e + 1.0f);
}
__device__ __forceinline__ unsigned short f2bf(float x) {
    union { __hip_bfloat16 b; unsigned short u; } v; v.b = __float2bfloat16(x); return v.u;
}
__device__ __forceinline__ float bf2f(unsigned short u) {
    union { unsigned int w; float f; } v; v.w = ((unsigned int)u) << 16; return v.f;
}
__device__ __forceinline__ unsigned int packsplit(float x) {
    unsigned short hi = f2bf(x);
    unsigned short lo = f2bf(x - bf2f(hi));
    return (unsigned)hi | ((unsigned)lo << 16);
}
__device__ __forceinline__ float unpacksplit(unsigned int u) {
    return bf2f((unsigned short)(u & 0xffffu)) + bf2f((unsigned short)(u >> 16));
}

// ---------------- prep: split-bf16 B matrices, chunk-interleaved ----------------
// Btu row n (768 B): 24 chunks x 32 B; chunk c = {8 k-hi bf16 (16B) | 8 k-lo bf16 (16B)},
//   k = 8c..8c+7. k<128: U rows; [128,192): W' rows. cols n<384: U_iou / 0.5*W_iou,
//   n in [384,512): U_f / W_f.
// Btl row n (256 B): 8 chunks x 32 B over k<64 of W_iou (leaf), n<384.
__global__ __launch_bounds__(256) void prep_bt(
    const float* __restrict__ U_iou, const float* __restrict__ U_f,
    const float* __restrict__ W_iou, const float* __restrict__ W_f,
    unsigned short* __restrict__ Btu, unsigned short* __restrict__ Btl)
{
    int t = blockIdx.x * 256 + threadIdx.x;
    float v[8];
    char* dst;
    if (t < 512 * 24) {
        int n = t / 24, cidx = t - n * 24;
        #pragma unroll
        for (int e = 0; e < 8; ++e) {
            int k = cidx * 8 + e;
            float x;
            if (k < 128) x = (n < 384) ? U_iou[k * 384 + n] : U_f[k * 128 + (n - 384)];
            else {
                int kf = k - 128;
                x = (n < 384) ? 0.5f * W_iou[kf * 384 + n] : W_f[kf * 128 + (n - 384)];
            }
            v[e] = x;
        }
        dst = (char*)Btu + (size_t)n * 768 + cidx * 32;
    } else {
        int t2 = t - 512 * 24;      // < 384*8
        int n = t2 >> 3, cidx = t2 & 7;
        #pragma unroll
        for (int e = 0; e < 8; ++e) v[e] = W_iou[(cidx * 8 + e) * 384 + n];
        dst = (char*)Btl + (size_t)n * 256 + cidx * 32;
    }
    unsigned int hi[4], lo[4];
    #pragma unroll
    for (int e = 0; e < 4; ++e) {
        unsigned short h0 = f2bf(v[2*e]), h1 = f2bf(v[2*e+1]);
        unsigned short s0 = f2bf(v[2*e] - bf2f(h0));
        unsigned short s1 = f2bf(v[2*e+1] - bf2f(h1));
        hi[e] = (unsigned)h0 | ((unsigned)h1 << 16);
        lo[e] = (unsigned)s0 | ((unsigned)s1 << 16);
    }
    *(uint4*)dst = make_uint4(hi[0], hi[1], hi[2], hi[3]);
    *(uint4*)(dst + 16) = make_uint4(lo[0], lo[1], lo[2], lo[3]);
}

#define MFMA(a, b, c) __builtin_amdgcn_mfma_f32_16x16x32_bf16(a, b, c, 0, 0, 0)

// ---------------- leaf GEMM: 64 leaves/block, 8 waves; B reg-double-buffered ----------------
// Wave w owns cols j = 16w..16w+15 for all 3 gates (ct = gate).
__global__ __launch_bounds__(512, 2) void leafgemm(
    const float* __restrict__ feat, const unsigned short* __restrict__ Btl,
    const float* __restrict__ b_iou,
    float* __restrict__ c_out, unsigned int* __restrict__ h2out)
{
    __shared__ __align__(16) char Alb[64 * 272];   // stride 272 => 2-way banks (free)
    const int tid = threadIdx.x;
    const int w = tid >> 6, l = tid & 63;
    const int l15 = l & 15, l4 = l >> 4;
    const int NB = blockIdx.x << 6;

    int nct[3];
    #pragma unroll
    for (int ct = 0; ct < 3; ++ct) nct[ct] = (ct << 7) + (w << 4) + l15;

    short8 Bh[2][3], Bl[2][3];
    #define LLOADB(buf, ss) { int chb = ((ss) << 2) + l4;                           \
        _Pragma("unroll") for (int ct = 0; ct < 3; ++ct) {                          \
            const char* bp = (const char*)Btl + (size_t)nct[ct] * 256 + (chb << 5); \
            Bh[buf][ct] = *(const short8*)(bp);                                     \
            Bl[buf][ct] = *(const short8*)(bp + 16); } }

    LLOADB(0, 0)   // overlap with A-stage

    // A stage: 64 rows x (8 hi + 8 lo) chunks; 1 task/thread
    {
        int row = tid >> 3, o = tid & 7;
        int leafidx = NB + row;
        int tree = leafidx >> 7;
        size_t grow = (size_t)(tree * S_NODES + 127 + (leafidx & 127));
        const float* fp = feat + grow * F_IN + (o << 3);
        float4 va = *(const float4*)(fp);
        float4 vb = *(const float4*)(fp + 4);
        float vv[8] = {va.x, va.y, va.z, va.w, vb.x, vb.y, vb.z, vb.w};
        unsigned int qh[4], ql[4];
        #pragma unroll
        for (int e = 0; e < 4; ++e) {
            unsigned short h0 = f2bf(vv[2*e]), h1 = f2bf(vv[2*e+1]);
            unsigned short s0 = f2bf(vv[2*e] - bf2f(h0));
            unsigned short s1 = f2bf(vv[2*e+1] - bf2f(h1));
            qh[e] = (unsigned)h0 | ((unsigned)h1 << 16);
            ql[e] = (unsigned)s0 | ((unsigned)s1 << 16);
        }
        char* arow = Alb + row * 272;
        *(uint4*)(arow + (o << 4)) = make_uint4(qh[0], qh[1], qh[2], qh[3]);
        *(uint4*)(arow + ((8 + o) << 4)) = make_uint4(ql[0], ql[1], ql[2], ql[3]);
    }
    __syncthreads();

    f32x4 acc[4][3];
    #pragma unroll
    for (int rt = 0; rt < 4; ++rt)
        #pragma unroll
        for (int ct = 0; ct < 3; ++ct) acc[rt][ct] = (f32x4){0,0,0,0};

    #pragma unroll
    for (int s = 0; s < 2; ++s) {
        const int cur = s & 1;
        if (s < 1) LLOADB(1, 1)
        int ch = (s << 2) + l4;
        short8 ah[4], al[4];
        #pragma unroll
        for (int rt = 0; rt < 4; ++rt) {
            const char* ap = Alb + (rt * 16 + l15) * 272;
            ah[rt] = *(const short8*)(ap + (ch << 4));
            al[rt] = *(const short8*)(ap + ((8 + ch) << 4));
        }
        #pragma unroll
        for (int ct = 0; ct < 3; ++ct)
            #pragma unroll
            for (int rt = 0; rt < 4; ++rt) {
                acc[rt][ct] = MFMA(ah[rt], Bh[cur][ct], acc[rt][ct]);
                acc[rt][ct] = MFMA(al[rt], Bh[cur][ct], acc[rt][ct]);
                acc[rt][ct] = MFMA(ah[rt], Bl[cur][ct], acc[rt][ct]);
            }
    }

    // epilogue: gates lane-local; C layout col=lane&15, row=(lane>>4)*4+reg
    const int j = (w << 4) + l15;
    float bi = b_iou[j], bo = b_iou[128 + j], bu = b_iou[256 + j];
    #pragma unroll
    for (int rt = 0; rt < 4; ++rt)
        #pragma unroll
        for (int rr = 0; rr < 4; ++rr) {
            int leafrow = rt * 16 + (l4 << 2) + rr;
            int leafidx = NB + leafrow;
            int tree = leafidx >> 7;
            size_t grow = (size_t)(tree * S_NODES + 127 + (leafidx & 127));
            float iv = acc[rt][0][rr] + bi;
            float ov = acc[rt][1][rr] + bo;
            float uv = acc[rt][2][rr] + bu;
            float cn = fsig(iv) * ftanh_(uv);
            float hn = fsig(ov) * ftanh_(cn);
            c_out[grow * 128 + j] = cn;
            h2out[grow * 128 + j] = packsplit(hn);
        }
    #undef LLOADB
}

// ---------------- internal-level GEMM: 32 nodes (64 child rows)/block, 8 waves ----------------
// A-row = [h_child(128) | feat_parent(64)] split-bf16 in LDS. B direct from Btu,
// register double-buffered across the 6 k-slices. Wave w owns cols j=16w..16w+15 x 4 gates.
// Handles ANY heap level (Lstart, Lbits) with (#nodes % 32 == 0) -> all levels L6..L0.
__global__ __launch_bounds__(512, 2) void ugemm(
    const float* __restrict__ feat, const unsigned int* __restrict__ h2,
    const unsigned short* __restrict__ Btu,
    const float* __restrict__ b_iou, const float* __restrict__ b_f,
    float* __restrict__ c_io, unsigned int* __restrict__ h2out,
    int Lstart, int Lbits)
{
    __shared__ __align__(16) char Alb[64 * 784];   // stride 784 => 2-way banks (free)
    const int tid = threadIdx.x;
    const int w = tid >> 6, l = tid & 63;
    const int l15 = l & 15, l4 = l >> 4;
    const int NB = blockIdx.x << 5;
    const int mask = (1 << Lbits) - 1;

    int nct[4];
    #pragma unroll
    for (int ct = 0; ct < 4; ++ct)
        nct[ct] = ((ct < 3) ? (ct << 7) : 384) + (w << 4) + l15;

    short8 Bh[2][4], Bl[2][4];
    #define ULOADB(buf, ss) { int chb = ((ss) << 2) + l4;                           \
        _Pragma("unroll") for (int ct = 0; ct < 4; ++ct) {                          \
            const char* bp = (const char*)Btu + (size_t)nct[ct] * 768 + (chb << 5); \
            Bh[buf][ct] = *(const short8*)(bp);                                     \
            Bl[buf][ct] = *(const short8*)(bp + 16); } }

    ULOADB(0, 0)   // overlap with A-stage

    // ---- A stage: 64 rows x 48 chunks (0..15 h-hi, 16..23 f-hi, 24..39 h-lo, 40..47 f-lo)
    #pragma unroll
    for (int i = 0; i < 2; ++i) {      // h tasks: 1024
        int tsk = tid + (i << 9);
        int row = tsk >> 4, o = tsk & 15;
        int node = NB + (row >> 1);
        int tree = node >> Lbits;
        int local = Lstart + (node & mask);
        size_t growc = (size_t)(tree * S_NODES + 2 * local + 1 + (row & 1));
        const unsigned int* hp = h2 + growc * 128 + (o << 3);
        uint4 a = *(const uint4*)(hp);
        uint4 b = *(const uint4*)(hp + 4);
        uint4 vh, vl;
        vh.x = (a.x & 0xffffu) | (a.y << 16);
        vh.y = (a.z & 0xffffu) | (a.w << 16);
        vh.z = (b.x & 0xffffu) | (b.y << 16);
        vh.w = (b.z & 0xffffu) | (b.w << 16);
        vl.x = (a.x >> 16) | (a.y & 0xffff0000u);
        vl.y = (a.z >> 16) | (a.w & 0xffff0000u);
        vl.z = (b.x >> 16) | (b.y & 0xffff0000u);
        vl.w = (b.z >> 16) | (b.w & 0xffff0000u);
        char* arow = Alb + row * 784;
        *(uint4*)(arow + (o << 4)) = vh;
        *(uint4*)(arow + ((24 + o) << 4)) = vl;
    }
    {                                   // feat tasks: 512
        int t2 = tid;
        int row = t2 >> 3, o = t2 & 7;
        int node = NB + (row >> 1);
        int tree = node >> Lbits;
        int local = Lstart + (node & mask);
        size_t growp = (size_t)(tree * S_NODES + local);
        const float* fp = feat + growp * F_IN + (o << 3);
        float4 va = *(const float4*)(fp);
        float4 vb = *(const float4*)(fp + 4);
        float vv[8] = {va.x, va.y, va.z, va.w, vb.x, vb.y, vb.z, vb.w};
        unsigned int qh[4], ql[4];
        #pragma unroll
        for (int e = 0; e < 4; ++e) {
            unsigned short h0 = f2bf(vv[2*e]), h1 = f2bf(vv[2*e+1]);
            unsigned short s0 = f2bf(vv[2*e] - bf2f(h0));
            unsigned short s1 = f2bf(vv[2*e+1] - bf2f(h1));
            qh[e] = (unsigned)h0 | ((unsigned)h1 << 16);
            ql[e] = (unsigned)s0 | ((unsigned)s1 << 16);
        }
        char* arow = Alb + row * 784;
        *(uint4*)(arow + ((16 + o) << 4)) = make_uint4(qh[0], qh[1], qh[2], qh[3]);
        *(uint4*)(arow + ((40 + o) << 4)) = make_uint4(ql[0], ql[1], ql[2], ql[3]);
    }
    __syncthreads();

    f32x4 acc[4][4];
    #pragma unroll
    for (int rt = 0; rt < 4; ++rt)
        #pragma unroll
        for (int ct = 0; ct < 4; ++ct) acc[rt][ct] = (f32x4){0,0,0,0};

    #pragma unroll
    for (int s = 0; s < 6; ++s) {
        const int cur = s & 1;
        if (s < 5) ULOADB(cur ^ 1, s + 1)
        int ch = (s << 2) + l4;
        short8 ah[4], al[4];
        #pragma unroll
        for (int rt = 0; rt < 4; ++rt) {
            const char* ap = Alb + (rt * 16 + l15) * 784;
            ah[rt] = *(const short8*)(ap + (ch << 4));
            al[rt] = *(const short8*)(ap + ((24 + ch) << 4));
        }
        #pragma unroll
        for (int ct = 0; ct < 4; ++ct)
            #pragma unroll
            for (int rt = 0; rt < 4; ++rt) {
                acc[rt][ct] = MFMA(ah[rt], Bh[cur][ct], acc[rt][ct]);
                acc[rt][ct] = MFMA(al[rt], Bh[cur][ct], acc[rt][ct]);
                acc[rt][ct] = MFMA(ah[rt], Bl[cur][ct], acc[rt][ct]);
            }
    }

    // ---- epilogue: gates lane-local; node m = rt*8 + l4*2 + p, child row-pair in rr ----
    const int j = (w << 4) + l15;
    float bi = b_iou[j], bo = b_iou[128 + j], bu = b_iou[256 + j], bfv = b_f[j];
    #pragma unroll
    for (int rt = 0; rt < 4; ++rt)
        #pragma unroll
        for (int p = 0; p < 2; ++p) {
            int m = rt * 8 + (l4 << 1) + p;
            int node = NB + m;
            int tree = node >> Lbits;
            int local = Lstart + (node & mask);
            size_t gp = (size_t)(tree * S_NODES + local);
            size_t gl = (size_t)(tree * S_NODES + 2 * local + 1);
            float iv = acc[rt][0][2*p] + acc[rt][0][2*p+1] + bi;
            float ov = acc[rt][1][2*p] + acc[rt][1][2*p+1] + bo;
            float uv = acc[rt][2][2*p] + acc[rt][2][2*p+1] + bu;
            float fl = fsig(acc[rt][3][2*p] + bfv);
            float fr = fsig(acc[rt][3][2*p+1] + bfv);
            float cl = c_io[gl * 128 + j];
            float cr = c_io[(gl + 1) * 128 + j];
            float cn = fsig(iv) * ftanh_(uv) + fl * cl + fr * cr;
            float hn = fsig(ov) * ftanh_(cn);
            c_io[gp * 128 + j] = cn;
            h2out[gp * 128 + j] = packsplit(hn);
        }
    #undef ULOADB
}

// ---------------- readout (h via h2 reconstruct) ----------------
__global__ __launch_bounds__(512) void readout_kernel(
    const unsigned int* __restrict__ h2,
    const float* __restrict__ lin1_w, const float* __restrict__ lin1_b,
    const float* __restrict__ lin2_w, const float* __restrict__ lin2_b,
    const float* __restrict__ lin_w, const float* __restrict__ lin_b,
    float* __restrict__ out)
{
    const int b = blockIdx.x;
    const int tid = threadIdx.x;
    const int q = tid >> 7;
    const int j = tid & 127;
    const unsigned int* hb = h2 + (size_t)b * S_NODES * H_DIM;

    float s = 0.f;
    #pragma unroll 4
    for (int n = q; n < S_NODES; n += 4) s += unpacksplit(hb[n * H_DIM + j]);

    __shared__ float part[4][H_DIM];
    __shared__ float xs[H_DIM];
    __shared__ float ys[H_DIM];
    __shared__ float red[2];

    part[q][j] = s;
    __syncthreads();
    if (tid < 128) {
        float t = (part[0][j] + part[1][j] + part[2][j] + part[3][j]) * (1.0f / 255.0f);
        xs[j] = fmaxf(t, 0.f);
    }
    __syncthreads();
    if (tid < 128) {
        float a = lin1_b[j];
        #pragma unroll 4
        for (int k = 0; k < H_DIM; ++k) a = fmaf(xs[k], lin1_w[k * H_DIM + j], a);
        ys[j] = fmaxf(a, 0.f);
    }
    __syncthreads();
    if (tid < 128) {
        float z = lin2_b[j];
        #pragma unroll 4
        for (int k = 0; k < H_DIM; ++k) z = fmaf(ys[k], lin2_w[k * H_DIM + j], z);
        z = fmaxf(z, 0.f);
        float t = z * lin_w[j];
        #pragma unroll
        for (int off = 32; off > 0; off >>= 1) t += __shfl_down(t, off, 64);
        if ((j & 63) == 0) red[j >> 6] = t;
    }
    __syncthreads();
    if (tid == 0) out[b] = red[0] + red[1] + lin_b[0];
}

extern "C" void kernel_launch(void* const* d_in, const int* in_sizes, int n_in,
                              void* d_out, int out_size, void* d_ws, size_t ws_size,
                              hipStream_t stream)
{
    const float* feat   = (const float*)d_in[0];
    const float* W_iou  = (const float*)d_in[1];
    const float* b_iou  = (const float*)d_in[2];
    const float* U_iou  = (const float*)d_in[3];
    const float* W_f    = (const float*)d_in[4];
    const float* b_f    = (const float*)d_in[5];
    const float* U_f    = (const float*)d_in[6];
    const float* lin1_w = (const float*)d_in[7];
    const float* lin1_b = (const float*)d_in[8];
    const float* lin2_w = (const float*)d_in[9];
    const float* lin2_b = (const float*)d_in[10];
    const float* lin_w  = (const float*)d_in[11];
    const float* lin_b  = (const float*)d_in[12];
    float* out = (float*)d_out;

    char* wsb = (char*)d_ws;
    unsigned short* Btu = (unsigned short*)wsb;                  // 384 KB
    unsigned short* Btl = (unsigned short*)(wsb + 393216);       // 96 KB
    float* c  = (float*)(wsb + 524288);                          // 33.4 MB
    unsigned int* h2 = (unsigned int*)(wsb + 524288 + (size_t)33423360); // 33.4 MB

    prep_bt<<<60, 256, 0, stream>>>(U_iou, U_f, W_iou, W_f, Btu, Btl);

    // leaves: heap L7, 32768 nodes, 64/block
    leafgemm<<<512, 512, 0, stream>>>(feat, Btl, b_iou, c, h2);

    // all internal levels via the same MFMA kernel: 32 nodes (64 child rows)/block
    ugemm<<<512, 512, 0, stream>>>(feat, h2, Btu, b_iou, b_f, c, h2, 63, 6); // L6: 16384
    ugemm<<<256, 512, 0, stream>>>(feat, h2, Btu, b_iou, b_f, c, h2, 31, 5); // L5: 8192
    ugemm<<<128, 512, 0, stream>>>(feat, h2, Btu, b_iou, b_f, c, h2, 15, 4); // L4: 4096
    ugemm<<<64,  512, 0, stream>>>(feat, h2, Btu, b_iou, b_f, c, h2,  7, 3); // L3: 2048
    ugemm<<<32,  512, 0, stream>>>(feat, h2, Btu, b_iou, b_f, c, h2,  3, 2); // L2: 1024
    ugemm<<<16,  512, 0, stream>>>(feat, h2, Btu, b_iou, b_f, c, h2,  1, 1); // L1: 512
    ugemm<<<8,   512, 0, stream>>>(feat, h2, Btu, b_iou, b_f, c, h2,  0, 0); // L0: 256

    readout_kernel<<<B_TREES, 512, 0, stream>>>(
        h2, lin1_w, lin1_b, lin2_w, lin2_b, lin_w, lin_b, out);
}

// Round 10
// 227.665 us; speedup vs baseline: 1.1935x; 1.1935x over previous
//
#include <hip/hip_runtime.h>
#include <hip/hip_bf16.h>
#include <math.h>

#define S_NODES 255
#define B_TREES 256
#define F_IN 64
#define H_DIM 128

typedef __attribute__((ext_vector_type(8))) short short8;
typedef __attribute__((ext_vector_type(4))) float f32x4;

__device__ __forceinline__ float fsig(float x) {
    float e = __expf(-x);
    return __builtin_amdgcn_rcpf(1.0f + e);
}
__device__ __forceinline__ float ftanh_(float x) {
    x = fminf(fmaxf(x, -15.0f), 15.0f);
    float e = __expf(2.0f * x);
    return (e - 1.0f) * __builtin_amdgcn_rcpf(e + 1.0f);
}
__device__ __forceinline__ unsigned short f2bf(float x) {
    union { __hip_bfloat16 b; unsigned short u; } v; v.b = __float2bfloat16(x); return v.u;
}
__device__ __forceinline__ float bf2f(unsigned short u) {
    union { unsigned int w; float f; } v; v.w = ((unsigned int)u) << 16; return v.f;
}
__device__ __forceinline__ unsigned int packsplit(float x) {
    unsigned short hi = f2bf(x);
    unsigned short lo = f2bf(x - bf2f(hi));
    return (unsigned)hi | ((unsigned)lo << 16);
}
__device__ __forceinline__ float unpacksplit(unsigned int u) {
    return bf2f((unsigned short)(u & 0xffffu)) + bf2f((unsigned short)(u >> 16));
}

// ---------------- prep: split-bf16 B matrices, chunk-interleaved ----------------
// Btu row n (768 B): 24 chunks x 32 B; chunk c = {8 k-hi bf16 (16B) | 8 k-lo bf16 (16B)},
//   k = 8c..8c+7. k<128: U rows; [128,192): W' rows. cols n<384: U_iou / 0.5*W_iou,
//   n in [384,512): U_f / W_f.
// Btl row n (256 B): 8 chunks x 32 B over k<64 of W_iou (leaf), n<384.
__global__ __launch_bounds__(256) void prep_bt(
    const float* __restrict__ U_iou, const float* __restrict__ U_f,
    const float* __restrict__ W_iou, const float* __restrict__ W_f,
    unsigned short* __restrict__ Btu, unsigned short* __restrict__ Btl)
{
    int t = blockIdx.x * 256 + threadIdx.x;
    float v[8];
    char* dst;
    if (t < 512 * 24) {
        int n = t / 24, cidx = t - n * 24;
        #pragma unroll
        for (int e = 0; e < 8; ++e) {
            int k = cidx * 8 + e;
            float x;
            if (k < 128) x = (n < 384) ? U_iou[k * 384 + n] : U_f[k * 128 + (n - 384)];
            else {
                int kf = k - 128;
                x = (n < 384) ? 0.5f * W_iou[kf * 384 + n] : W_f[kf * 128 + (n - 384)];
            }
            v[e] = x;
        }
        dst = (char*)Btu + (size_t)n * 768 + cidx * 32;
    } else {
        int t2 = t - 512 * 24;      // < 384*8
        int n = t2 >> 3, cidx = t2 & 7;
        #pragma unroll
        for (int e = 0; e < 8; ++e) v[e] = W_iou[(cidx * 8 + e) * 384 + n];
        dst = (char*)Btl + (size_t)n * 256 + cidx * 32;
    }
    unsigned int hi[4], lo[4];
    #pragma unroll
    for (int e = 0; e < 4; ++e) {
        unsigned short h0 = f2bf(v[2*e]), h1 = f2bf(v[2*e+1]);
        unsigned short s0 = f2bf(v[2*e] - bf2f(h0));
        unsigned short s1 = f2bf(v[2*e+1] - bf2f(h1));
        hi[e] = (unsigned)h0 | ((unsigned)h1 << 16);
        lo[e] = (unsigned)s0 | ((unsigned)s1 << 16);
    }
    *(uint4*)dst = make_uint4(hi[0], hi[1], hi[2], hi[3]);
    *(uint4*)(dst + 16) = make_uint4(lo[0], lo[1], lo[2], lo[3]);
}

#define MFMA(a, b, c) __builtin_amdgcn_mfma_f32_16x16x32_bf16(a, b, c, 0, 0, 0)

// ---------------- leaf GEMM: 64 leaves/block, 8 waves; B reg-double-buffered ----------------
__global__ __launch_bounds__(512, 2) void leafgemm(
    const float* __restrict__ feat, const unsigned short* __restrict__ Btl,
    const float* __restrict__ b_iou,
    float* __restrict__ c_out, unsigned int* __restrict__ h2out)
{
    __shared__ __align__(16) char Alb[64 * 272];   // stride 272 => 2-way banks (free)
    const int tid = threadIdx.x;
    const int w = tid >> 6, l = tid & 63;
    const int l15 = l & 15, l4 = l >> 4;
    const int NB = blockIdx.x << 6;

    int nct[3];
    #pragma unroll
    for (int ct = 0; ct < 3; ++ct) nct[ct] = (ct << 7) + (w << 4) + l15;

    short8 Bh[2][3], Bl[2][3];
    #define LLOADB(buf, ss) { int chb = ((ss) << 2) + l4;                           \
        _Pragma("unroll") for (int ct = 0; ct < 3; ++ct) {                          \
            const char* bp = (const char*)Btl + (size_t)nct[ct] * 256 + (chb << 5); \
            Bh[buf][ct] = *(const short8*)(bp);                                     \
            Bl[buf][ct] = *(const short8*)(bp + 16); } }

    LLOADB(0, 0)   // overlap with A-stage

    // A stage: 64 rows x (8 hi + 8 lo) chunks; 1 task/thread
    {
        int row = tid >> 3, o = tid & 7;
        int leafidx = NB + row;
        int tree = leafidx >> 7;
        size_t grow = (size_t)(tree * S_NODES + 127 + (leafidx & 127));
        const float* fp = feat + grow * F_IN + (o << 3);
        float4 va = *(const float4*)(fp);
        float4 vb = *(const float4*)(fp + 4);
        float vv[8] = {va.x, va.y, va.z, va.w, vb.x, vb.y, vb.z, vb.w};
        unsigned int qh[4], ql[4];
        #pragma unroll
        for (int e = 0; e < 4; ++e) {
            unsigned short h0 = f2bf(vv[2*e]), h1 = f2bf(vv[2*e+1]);
            unsigned short s0 = f2bf(vv[2*e] - bf2f(h0));
            unsigned short s1 = f2bf(vv[2*e+1] - bf2f(h1));
            qh[e] = (unsigned)h0 | ((unsigned)h1 << 16);
            ql[e] = (unsigned)s0 | ((unsigned)s1 << 16);
        }
        char* arow = Alb + row * 272;
        *(uint4*)(arow + (o << 4)) = make_uint4(qh[0], qh[1], qh[2], qh[3]);
        *(uint4*)(arow + ((8 + o) << 4)) = make_uint4(ql[0], ql[1], ql[2], ql[3]);
    }
    __syncthreads();

    f32x4 acc[4][3];
    #pragma unroll
    for (int rt = 0; rt < 4; ++rt)
        #pragma unroll
        for (int ct = 0; ct < 3; ++ct) acc[rt][ct] = (f32x4){0,0,0,0};

    #pragma unroll
    for (int s = 0; s < 2; ++s) {
        const int cur = s & 1;
        if (s < 1) LLOADB(1, 1)
        int ch = (s << 2) + l4;
        short8 ah[4], al[4];
        #pragma unroll
        for (int rt = 0; rt < 4; ++rt) {
            const char* ap = Alb + (rt * 16 + l15) * 272;
            ah[rt] = *(const short8*)(ap + (ch << 4));
            al[rt] = *(const short8*)(ap + ((8 + ch) << 4));
        }
        #pragma unroll
        for (int ct = 0; ct < 3; ++ct)
            #pragma unroll
            for (int rt = 0; rt < 4; ++rt) {
                acc[rt][ct] = MFMA(ah[rt], Bh[cur][ct], acc[rt][ct]);
                acc[rt][ct] = MFMA(al[rt], Bh[cur][ct], acc[rt][ct]);
                acc[rt][ct] = MFMA(ah[rt], Bl[cur][ct], acc[rt][ct]);
            }
    }

    // epilogue: gates lane-local; C layout col=lane&15, row=(lane>>4)*4+reg
    const int j = (w << 4) + l15;
    float bi = b_iou[j], bo = b_iou[128 + j], bu = b_iou[256 + j];
    #pragma unroll
    for (int rt = 0; rt < 4; ++rt)
        #pragma unroll
        for (int rr = 0; rr < 4; ++rr) {
            int leafrow = rt * 16 + (l4 << 2) + rr;
            int leafidx = NB + leafrow;
            int tree = leafidx >> 7;
            size_t grow = (size_t)(tree * S_NODES + 127 + (leafidx & 127));
            float iv = acc[rt][0][rr] + bi;
            float ov = acc[rt][1][rr] + bo;
            float uv = acc[rt][2][rr] + bu;
            float cn = fsig(iv) * ftanh_(uv);
            float hn = fsig(ov) * ftanh_(cn);
            c_out[grow * 128 + j] = cn;
            h2out[grow * 128 + j] = packsplit(hn);
        }
    #undef LLOADB
}

// ---------------- internal-level GEMM: 32 nodes (64 child rows)/block, 8 waves ----------------
// Used for heap L6/L5/L4 (grids 512/256/128).
__global__ __launch_bounds__(512, 2) void ugemm(
    const float* __restrict__ feat, const unsigned int* __restrict__ h2,
    const unsigned short* __restrict__ Btu,
    const float* __restrict__ b_iou, const float* __restrict__ b_f,
    float* __restrict__ c_io, unsigned int* __restrict__ h2out,
    int Lstart, int Lbits)
{
    __shared__ __align__(16) char Alb[64 * 784];   // stride 784 => 2-way banks (free)
    const int tid = threadIdx.x;
    const int w = tid >> 6, l = tid & 63;
    const int l15 = l & 15, l4 = l >> 4;
    const int NB = blockIdx.x << 5;
    const int mask = (1 << Lbits) - 1;

    int nct[4];
    #pragma unroll
    for (int ct = 0; ct < 4; ++ct)
        nct[ct] = ((ct < 3) ? (ct << 7) : 384) + (w << 4) + l15;

    short8 Bh[2][4], Bl[2][4];
    #define ULOADB(buf, ss) { int chb = ((ss) << 2) + l4;                           \
        _Pragma("unroll") for (int ct = 0; ct < 4; ++ct) {                          \
            const char* bp = (const char*)Btu + (size_t)nct[ct] * 768 + (chb << 5); \
            Bh[buf][ct] = *(const short8*)(bp);                                     \
            Bl[buf][ct] = *(const short8*)(bp + 16); } }

    ULOADB(0, 0)   // overlap with A-stage

    // ---- A stage: 64 rows x 48 chunks (0..15 h-hi, 16..23 f-hi, 24..39 h-lo, 40..47 f-lo)
    #pragma unroll
    for (int i = 0; i < 2; ++i) {      // h tasks: 1024
        int tsk = tid + (i << 9);
        int row = tsk >> 4, o = tsk & 15;
        int node = NB + (row >> 1);
        int tree = node >> Lbits;
        int local = Lstart + (node & mask);
        size_t growc = (size_t)(tree * S_NODES + 2 * local + 1 + (row & 1));
        const unsigned int* hp = h2 + growc * 128 + (o << 3);
        uint4 a = *(const uint4*)(hp);
        uint4 b = *(const uint4*)(hp + 4);
        uint4 vh, vl;
        vh.x = (a.x & 0xffffu) | (a.y << 16);
        vh.y = (a.z & 0xffffu) | (a.w << 16);
        vh.z = (b.x & 0xffffu) | (b.y << 16);
        vh.w = (b.z & 0xffffu) | (b.w << 16);
        vl.x = (a.x >> 16) | (a.y & 0xffff0000u);
        vl.y = (a.z >> 16) | (a.w & 0xffff0000u);
        vl.z = (b.x >> 16) | (b.y & 0xffff0000u);
        vl.w = (b.z >> 16) | (b.w & 0xffff0000u);
        char* arow = Alb + row * 784;
        *(uint4*)(arow + (o << 4)) = vh;
        *(uint4*)(arow + ((24 + o) << 4)) = vl;
    }
    {                                   // feat tasks: 512
        int t2 = tid;
        int row = t2 >> 3, o = t2 & 7;
        int node = NB + (row >> 1);
        int tree = node >> Lbits;
        int local = Lstart + (node & mask);
        size_t growp = (size_t)(tree * S_NODES + local);
        const float* fp = feat + growp * F_IN + (o << 3);
        float4 va = *(const float4*)(fp);
        float4 vb = *(const float4*)(fp + 4);
        float vv[8] = {va.x, va.y, va.z, va.w, vb.x, vb.y, vb.z, vb.w};
        unsigned int qh[4], ql[4];
        #pragma unroll
        for (int e = 0; e < 4; ++e) {
            unsigned short h0 = f2bf(vv[2*e]), h1 = f2bf(vv[2*e+1]);
            unsigned short s0 = f2bf(vv[2*e] - bf2f(h0));
            unsigned short s1 = f2bf(vv[2*e+1] - bf2f(h1));
            qh[e] = (unsigned)h0 | ((unsigned)h1 << 16);
            ql[e] = (unsigned)s0 | ((unsigned)s1 << 16);
        }
        char* arow = Alb + row * 784;
        *(uint4*)(arow + ((16 + o) << 4)) = make_uint4(qh[0], qh[1], qh[2], qh[3]);
        *(uint4*)(arow + ((40 + o) << 4)) = make_uint4(ql[0], ql[1], ql[2], ql[3]);
    }
    __syncthreads();

    f32x4 acc[4][4];
    #pragma unroll
    for (int rt = 0; rt < 4; ++rt)
        #pragma unroll
        for (int ct = 0; ct < 4; ++ct) acc[rt][ct] = (f32x4){0,0,0,0};

    #pragma unroll
    for (int s = 0; s < 6; ++s) {
        const int cur = s & 1;
        if (s < 5) ULOADB(cur ^ 1, s + 1)
        int ch = (s << 2) + l4;
        short8 ah[4], al[4];
        #pragma unroll
        for (int rt = 0; rt < 4; ++rt) {
            const char* ap = Alb + (rt * 16 + l15) * 784;
            ah[rt] = *(const short8*)(ap + (ch << 4));
            al[rt] = *(const short8*)(ap + ((24 + ch) << 4));
        }
        #pragma unroll
        for (int ct = 0; ct < 4; ++ct)
            #pragma unroll
            for (int rt = 0; rt < 4; ++rt) {
                acc[rt][ct] = MFMA(ah[rt], Bh[cur][ct], acc[rt][ct]);
                acc[rt][ct] = MFMA(al[rt], Bh[cur][ct], acc[rt][ct]);
                acc[rt][ct] = MFMA(ah[rt], Bl[cur][ct], acc[rt][ct]);
            }
    }

    // ---- epilogue: gates lane-local; node m = rt*8 + l4*2 + p, child row-pair in rr ----
    const int j = (w << 4) + l15;
    float bi = b_iou[j], bo = b_iou[128 + j], bu = b_iou[256 + j], bfv = b_f[j];
    #pragma unroll
    for (int rt = 0; rt < 4; ++rt)
        #pragma unroll
        for (int p = 0; p < 2; ++p) {
            int m = rt * 8 + (l4 << 1) + p;
            int node = NB + m;
            int tree = node >> Lbits;
            int local = Lstart + (node & mask);
            size_t gp = (size_t)(tree * S_NODES + local);
            size_t gl = (size_t)(tree * S_NODES + 2 * local + 1);
            float iv = acc[rt][0][2*p] + acc[rt][0][2*p+1] + bi;
            float ov = acc[rt][1][2*p] + acc[rt][1][2*p+1] + bo;
            float uv = acc[rt][2][2*p] + acc[rt][2][2*p+1] + bu;
            float fl = fsig(acc[rt][3][2*p] + bfv);
            float fr = fsig(acc[rt][3][2*p+1] + bfv);
            float cl = c_io[gl * 128 + j];
            float cr = c_io[(gl + 1) * 128 + j];
            float cn = fsig(iv) * ftanh_(uv) + fl * cl + fr * cr;
            float hn = fsig(ov) * ftanh_(cn);
            c_io[gp * 128 + j] = cn;
            h2out[gp * 128 + j] = packsplit(hn);
        }
    #undef ULOADB
}

// ---------------- fused top tile: heap L3..L0, 1 block/tree, subtree in LDS ----------------
// M=16 variant of ugemm run 4x level-serially. Children of L3 staged from global
// (L4 outputs); all deeper levels read/write h2/c in LDS. Invalid rows (cnt<8)
// compute finite garbage, skipped at epilogue.
__global__ __launch_bounds__(512, 2) void toptile(
    const float* __restrict__ feat, const unsigned int* __restrict__ h2g,
    const float* __restrict__ c_g, const unsigned short* __restrict__ Btu,
    const float* __restrict__ b_iou, const float* __restrict__ b_f,
    unsigned int* __restrict__ h2out)
{
    __shared__ unsigned int h2s[31][H_DIM];           // 15.9 KB
    __shared__ float cs[31][H_DIM];                   // 15.9 KB
    __shared__ __align__(16) char Alb[16 * 784];      // 12.3 KB
    const int tid = threadIdx.x;
    const int w = tid >> 6, l = tid & 63;
    const int l15 = l & 15, l4 = l >> 4;
    const size_t tb = (size_t)blockIdx.x * S_NODES;

    // stage children of L3: locals 15..30 (h2 + c), one uint4/float4 per thread
    {
        int row = tid >> 5, c4 = (tid & 31) << 2;
        *(uint4*)&h2s[15 + row][c4] = *(const uint4*)(h2g + (tb + 15 + row) * H_DIM + c4);
        *(float4*)&cs[15 + row][c4] = *(const float4*)(c_g + (tb + 15 + row) * H_DIM + c4);
    }
    __syncthreads();

    int nct[4];
    #pragma unroll
    for (int ct = 0; ct < 4; ++ct)
        nct[ct] = ((ct < 3) ? (ct << 7) : 384) + (w << 4) + l15;

    const int j = (w << 4) + l15;
    const float bi = b_iou[j], bo = b_iou[128 + j], bu = b_iou[256 + j], bfv = b_f[j];

    const int bases[4] = {7, 3, 1, 0};
    const int cnts[4]  = {8, 4, 2, 1};

    for (int lev = 0; lev < 4; ++lev) {
        const int base = bases[lev], cnt = cnts[lev];
        const int rows = cnt << 1;

        // ---- A build (rows*24 tasks; chunk layout identical to ugemm) ----
        if (tid < rows * 16) {
            int r = tid >> 4, o = tid & 15;
            int child = 2 * (base + (r >> 1)) + 1 + (r & 1);
            const unsigned int* hp = &h2s[child][o << 3];
            unsigned int u0 = hp[0], u1 = hp[1], u2 = hp[2], u3 = hp[3];
            unsigned int u4 = hp[4], u5 = hp[5], u6 = hp[6], u7 = hp[7];
            uint4 vh, vl;
            vh.x = (u0 & 0xffffu) | (u1 << 16);
            vh.y = (u2 & 0xffffu) | (u3 << 16);
            vh.z = (u4 & 0xffffu) | (u5 << 16);
            vh.w = (u6 & 0xffffu) | (u7 << 16);
            vl.x = (u0 >> 16) | (u1 & 0xffff0000u);
            vl.y = (u2 >> 16) | (u3 & 0xffff0000u);
            vl.z = (u4 >> 16) | (u5 & 0xffff0000u);
            vl.w = (u6 >> 16) | (u7 & 0xffff0000u);
            char* arow = Alb + r * 784;
            *(uint4*)(arow + (o << 4)) = vh;
            *(uint4*)(arow + ((24 + o) << 4)) = vl;
        } else if (tid < rows * 24) {
            int t2 = tid - rows * 16;
            int r = t2 >> 3, o = t2 & 7;
            int parent = base + (r >> 1);
            const float* fp = feat + (tb + parent) * F_IN + (o << 3);
            float4 va = *(const float4*)(fp);
            float4 vb = *(const float4*)(fp + 4);
            float vv[8] = {va.x, va.y, va.z, va.w, vb.x, vb.y, vb.z, vb.w};
            unsigned int qh[4], ql[4];
            #pragma unroll
            for (int e = 0; e < 4; ++e) {
                unsigned short h0 = f2bf(vv[2*e]), h1 = f2bf(vv[2*e+1]);
                unsigned short s0 = f2bf(vv[2*e] - bf2f(h0));
                unsigned short s1 = f2bf(vv[2*e+1] - bf2f(h1));
                qh[e] = (unsigned)h0 | ((unsigned)h1 << 16);
                ql[e] = (unsigned)s0 | ((unsigned)s1 << 16);
            }
            char* arow = Alb + r * 784;
            *(uint4*)(arow + ((16 + o) << 4)) = make_uint4(qh[0], qh[1], qh[2], qh[3]);
            *(uint4*)(arow + ((40 + o) << 4)) = make_uint4(ql[0], ql[1], ql[2], ql[3]);
        }
        __syncthreads();

        // ---- M=16 GEMM: B direct from Btu, reg double-buffered ----
        f32x4 acc[4];
        #pragma unroll
        for (int ct = 0; ct < 4; ++ct) acc[ct] = (f32x4){0,0,0,0};
        short8 Bh[2][4], Bl[2][4];
        #define TLOADB(buf, ss) { int chb = ((ss) << 2) + l4;                           \
            _Pragma("unroll") for (int ct = 0; ct < 4; ++ct) {                          \
                const char* bp = (const char*)Btu + (size_t)nct[ct] * 768 + (chb << 5); \
                Bh[buf][ct] = *(const short8*)(bp);                                     \
                Bl[buf][ct] = *(const short8*)(bp + 16); } }
        TLOADB(0, 0)
        #pragma unroll
        for (int s = 0; s < 6; ++s) {
            const int cur = s & 1;
            if (s < 5) TLOADB(cur ^ 1, s + 1)
            int ch = (s << 2) + l4;
            const char* ap = Alb + l15 * 784;
            short8 ah = *(const short8*)(ap + (ch << 4));
            short8 al = *(const short8*)(ap + ((24 + ch) << 4));
            #pragma unroll
            for (int ct = 0; ct < 4; ++ct) {
                acc[ct] = MFMA(ah, Bh[cur][ct], acc[ct]);
                acc[ct] = MFMA(al, Bh[cur][ct], acc[ct]);
                acc[ct] = MFMA(ah, Bl[cur][ct], acc[ct]);
            }
        }
        #undef TLOADB

        // ---- epilogue: node m = l4*2 + p; skip m >= cnt ----
        #pragma unroll
        for (int p = 0; p < 2; ++p) {
            int m = (l4 << 1) + p;
            if (m < cnt) {
                int local = base + m;
                float iv = acc[0][2*p] + acc[0][2*p+1] + bi;
                float ov = acc[1][2*p] + acc[1][2*p+1] + bo;
                float uv = acc[2][2*p] + acc[2][2*p+1] + bu;
                float fl = fsig(acc[3][2*p] + bfv);
                float fr = fsig(acc[3][2*p+1] + bfv);
                float cl = cs[2*local+1][j];
                float cr = cs[2*local+2][j];
                float cn = fsig(iv) * ftanh_(uv) + fl * cl + fr * cr;
                float hn = fsig(ov) * ftanh_(cn);
                cs[local][j] = cn;
                unsigned int pk = packsplit(hn);
                h2s[local][j] = pk;
                h2out[(tb + local) * H_DIM + j] = pk;
            }
        }
        __syncthreads();
    }
}

// ---------------- readout (h via h2 reconstruct) ----------------
__global__ __launch_bounds__(512) void readout_kernel(
    const unsigned int* __restrict__ h2,
    const float* __restrict__ lin1_w, const float* __restrict__ lin1_b,
    const float* __restrict__ lin2_w, const float* __restrict__ lin2_b,
    const float* __restrict__ lin_w, const float* __restrict__ lin_b,
    float* __restrict__ out)
{
    const int b = blockIdx.x;
    const int tid = threadIdx.x;
    const int q = tid >> 7;
    const int j = tid & 127;
    const unsigned int* hb = h2 + (size_t)b * S_NODES * H_DIM;

    float s = 0.f;
    #pragma unroll 4
    for (int n = q; n < S_NODES; n += 4) s += unpacksplit(hb[n * H_DIM + j]);

    __shared__ float part[4][H_DIM];
    __shared__ float xs[H_DIM];
    __shared__ float ys[H_DIM];
    __shared__ float red[2];

    part[q][j] = s;
    __syncthreads();
    if (tid < 128) {
        float t = (part[0][j] + part[1][j] + part[2][j] + part[3][j]) * (1.0f / 255.0f);
        xs[j] = fmaxf(t, 0.f);
    }
    __syncthreads();
    if (tid < 128) {
        float a = lin1_b[j];
        #pragma unroll 4
        for (int k = 0; k < H_DIM; ++k) a = fmaf(xs[k], lin1_w[k * H_DIM + j], a);
        ys[j] = fmaxf(a, 0.f);
    }
    __syncthreads();
    if (tid < 128) {
        float z = lin2_b[j];
        #pragma unroll 4
        for (int k = 0; k < H_DIM; ++k) z = fmaf(ys[k], lin2_w[k * H_DIM + j], z);
        z = fmaxf(z, 0.f);
        float t = z * lin_w[j];
        #pragma unroll
        for (int off = 32; off > 0; off >>= 1) t += __shfl_down(t, off, 64);
        if ((j & 63) == 0) red[j >> 6] = t;
    }
    __syncthreads();
    if (tid == 0) out[b] = red[0] + red[1] + lin_b[0];
}

extern "C" void kernel_launch(void* const* d_in, const int* in_sizes, int n_in,
                              void* d_out, int out_size, void* d_ws, size_t ws_size,
                              hipStream_t stream)
{
    const float* feat   = (const float*)d_in[0];
    const float* W_iou  = (const float*)d_in[1];
    const float* b_iou  = (const float*)d_in[2];
    const float* U_iou  = (const float*)d_in[3];
    const float* W_f    = (const float*)d_in[4];
    const float* b_f    = (const float*)d_in[5];
    const float* U_f    = (const float*)d_in[6];
    const float* lin1_w = (const float*)d_in[7];
    const float* lin1_b = (const float*)d_in[8];
    const float* lin2_w = (const float*)d_in[9];
    const float* lin2_b = (const float*)d_in[10];
    const float* lin_w  = (const float*)d_in[11];
    const float* lin_b  = (const float*)d_in[12];
    float* out = (float*)d_out;

    char* wsb = (char*)d_ws;
    unsigned short* Btu = (unsigned short*)wsb;                  // 384 KB
    unsigned short* Btl = (unsigned short*)(wsb + 393216);       // 96 KB
    float* c  = (float*)(wsb + 524288);                          // 33.4 MB
    unsigned int* h2 = (unsigned int*)(wsb + 524288 + (size_t)33423360); // 33.4 MB

    prep_bt<<<60, 256, 0, stream>>>(U_iou, U_f, W_iou, W_f, Btu, Btl);

    // leaves: heap L7, 32768 nodes, 64/block
    leafgemm<<<512, 512, 0, stream>>>(feat, Btl, b_iou, c, h2);

    // big internal levels: 32 nodes (64 child rows)/block
    ugemm<<<512, 512, 0, stream>>>(feat, h2, Btu, b_iou, b_f, c, h2, 63, 6); // L6: 16384
    ugemm<<<256, 512, 0, stream>>>(feat, h2, Btu, b_iou, b_f, c, h2, 31, 5); // L5: 8192
    ugemm<<<128, 512, 0, stream>>>(feat, h2, Btu, b_iou, b_f, c, h2, 15, 4); // L4: 4096

    // heap L3..L0 fused, one block per tree, subtree resident in LDS
    toptile<<<B_TREES, 512, 0, stream>>>(feat, h2, c, Btu, b_iou, b_f, h2);

    readout_kernel<<<B_TREES, 512, 0, stream>>>(
        h2, lin1_w, lin1_b, lin2_w, lin2_b, lin_w, lin_b, out);
}